// Round 6
// baseline (1127.670 us; speedup 1.0000x reference)
//
#include <hip/hip_runtime.h>
#include <hip/hip_bf16.h>
#include <math.h>

#define D 128

// ---------------- wave helpers ----------------

__device__ __forceinline__ float waveSum(float v){
    #pragma unroll
    for (int m = 1; m < 64; m <<= 1) v += __shfl_xor(v, m, 64);
    return v;
}

__device__ __forceinline__ float rdlane(float v, int lane){
    return __int_as_float(__builtin_amdgcn_readlane(__float_as_int(v), lane));
}

__device__ __forceinline__ float gelu_exact(float x){
    return 0.5f * x * (1.0f + erff(x * 0.70710678118654752f));
}

// ---------------- LDS helpers (used by pull kernels) ----------------

template<int R>
__device__ __forceinline__ void multiReduce(float* red, int j){
    __syncthreads();
    #pragma unroll
    for (int s = 64; s > 0; s >>= 1){
        if (j < s){
            #pragma unroll
            for (int r = 0; r < R; ++r) red[r*D + j] += red[r*D + j + s];
        }
        __syncthreads();
    }
}

template<int R>
__device__ __forceinline__ void matvec(const float* sh, const float* __restrict__ W,
                                       const float* __restrict__ bias, int j, float* acc){
    float bb = bias[j];
    #pragma unroll
    for (int r = 0; r < R; ++r) acc[r] = bb;
    #pragma unroll 8
    for (int i = 0; i < D; ++i){
        float w = W[i*D + j];
        #pragma unroll
        for (int r = 0; r < R; ++r) acc[r] += sh[r*D + i] * w;
    }
}

// ---------------- dense transformer block: readlane form, LDS-free ----------------
// 1 wave/block, RB=16 rows/block, each lane owns cols (2l, 2l+1).
// y[r][i] broadcast via v_readlane -> SGPR operand of v_fmac (no LDS, no barriers).
#define RB 16

// acc{0,1}[r] = bias[c] + sum_i y[r][i] * W[i][c] for c = 2l, 2l+1
__device__ __forceinline__ void rl_matvec(const float* y0, const float* y1,
                                          const float* __restrict__ W,
                                          const float* __restrict__ bias,
                                          int c0, float* a0, float* a1)
{
    float2 bb = *(const float2*)&bias[c0];
    #pragma unroll
    for (int r = 0; r < RB; ++r){ a0[r] = bb.x; a1[r] = bb.y; }
    #pragma unroll 4
    for (int i = 0; i < D; i += 2){
        float2 wA = *(const float2*)&W[(size_t)i*D + c0];        // row i
        float2 wB = *(const float2*)&W[(size_t)(i+1)*D + c0];    // row i+1
        int half = i >> 1;
        #pragma unroll
        for (int r = 0; r < RB; ++r){
            float sA = rdlane(y0[r], half);   // y[r][i]   (col i stored: lane i/2, reg i&1)
            a0[r] += sA * wA.x; a1[r] += sA * wA.y;
        }
        #pragma unroll
        for (int r = 0; r < RB; ++r){
            float sB = rdlane(y1[r], half);   // y[r][i+1]
            a0[r] += sB * wB.x; a1[r] += sB * wB.y;
        }
    }
}

__global__ __launch_bounds__(64)
void k_dense(const float* __restrict__ ent,
             const float* __restrict__ g1, const float* __restrict__ be1,
             const float* __restrict__ wv, const float* __restrict__ bv,
             const float* __restrict__ wo, const float* __restrict__ bo,
             const float* __restrict__ g2, const float* __restrict__ be2,
             const float* __restrict__ w1, const float* __restrict__ b1,
             const float* __restrict__ w2, const float* __restrict__ b2,
             float* __restrict__ gcn_in, int n)
{
    const int l  = threadIdx.x;          // 0..63
    const int c0 = 2*l;                  // this lane's two columns
    const int row0 = blockIdx.x * RB;

    float2 g1v = *(const float2*)&g1[c0],  b1v = *(const float2*)&be1[c0];
    float2 g2v = *(const float2*)&g2[c0],  b2v = *(const float2*)&be2[c0];

    // load entity rows (coalesced float2)
    float e0[RB], e1[RB];
    #pragma unroll
    for (int r = 0; r < RB; ++r){
        int rr = row0 + r;
        if (rr < n){ float2 t = *(const float2*)&ent[(size_t)rr*D + c0]; e0[r]=t.x; e1[r]=t.y; }
        else       { e0[r]=0.0f; e1[r]=0.0f; }
    }

    // ---- LN1 (wave-shuffle reductions) ----
    float y0[RB], y1[RB];
    #pragma unroll
    for (int r = 0; r < RB; ++r){
        float mu = waveSum(e0[r] + e1[r]) * (1.0f/D);
        float d0 = e0[r]-mu, d1 = e1[r]-mu;
        float var = waveSum(d0*d0 + d1*d1) * (1.0f/D);
        float rs = rsqrtf(var + 1e-5f);
        y0[r] = d0*rs*g1v.x + b1v.x;
        y1[r] = d1*rs*g1v.y + b1v.y;
    }

    // ---- v = y@wv + bv ; ctx == v (softmax over length-1 seq == 1) ----
    float v0[RB], v1[RB];
    rl_matvec(y0, y1, wv, bv, c0, v0, v1);

    // ---- x = e + v@wo + bo ----
    float x0[RB], x1[RB];
    rl_matvec(v0, v1, wo, bo, c0, x0, x1);
    #pragma unroll
    for (int r = 0; r < RB; ++r){ x0[r] += e0[r]; x1[r] += e1[r]; }

    // ---- LN2 (reuse y regs) ----
    #pragma unroll
    for (int r = 0; r < RB; ++r){
        float mu = waveSum(x0[r] + x1[r]) * (1.0f/D);
        float d0 = x0[r]-mu, d1 = x1[r]-mu;
        float var = waveSum(d0*d0 + d1*d1) * (1.0f/D);
        float rs = rsqrtf(var + 1e-5f);
        y0[r] = d0*rs*g2v.x + b2v.x;
        y1[r] = d1*rs*g2v.y + b2v.y;
    }

    // ---- h = gelu(y2@w1 + b1) (reuse v regs) ----
    rl_matvec(y0, y1, w1, b1, c0, v0, v1);
    #pragma unroll
    for (int r = 0; r < RB; ++r){ v0[r] = gelu_exact(v0[r]); v1[r] = gelu_exact(v1[r]); }

    // ---- gcn_in = x + h@w2 + b2 (reuse y regs as acc) ----
    rl_matvec(v0, v1, w2, b2, c0, y0, y1);
    #pragma unroll
    for (int r = 0; r < RB; ++r){
        int rr = row0 + r;
        if (rr < n){
            float2 o; o.x = x0[r] + y0[r]; o.y = x1[r] + y1[r];
            *(float2*)&gcn_in[(size_t)rr*D + c0] = o;
        }
    }
}

// ---------------- device CSR build (unchanged) ----------------

__global__ __launch_bounds__(256)
void k_hist(const int* __restrict__ rows, int* __restrict__ deg, int E){
    int i = blockIdx.x * 256 + threadIdx.x;
    if (i < E) atomicAdd(&deg[rows[i]], 1);
}

__global__ __launch_bounds__(256)
void k_scan_partial(const int* __restrict__ deg, int* __restrict__ bsum, int n){
    __shared__ int s[256];
    int i = blockIdx.x * 256 + threadIdx.x;
    s[threadIdx.x] = (i < n) ? deg[i] : 0;
    __syncthreads();
    #pragma unroll
    for (int st = 128; st > 0; st >>= 1){
        if (threadIdx.x < st) s[threadIdx.x] += s[threadIdx.x + st];
        __syncthreads();
    }
    if (threadIdx.x == 0) bsum[blockIdx.x] = s[0];
}

__global__ __launch_bounds__(1024)
void k_scan_bsums(int* __restrict__ bsum, int nb){
    __shared__ int a[1024], b[1024];
    int t = threadIdx.x;
    int orig = (t < nb) ? bsum[t] : 0;
    int *src = a, *dst = b;
    src[t] = orig;
    __syncthreads();
    for (int off = 1; off < 1024; off <<= 1){
        dst[t] = src[t] + ((t >= off) ? src[t-off] : 0);
        __syncthreads();
        int* tmp = src; src = dst; dst = tmp;
    }
    if (t < nb) bsum[t] = src[t] - orig;   // exclusive
}

__global__ __launch_bounds__(256)
void k_scan_final(const int* __restrict__ deg, const int* __restrict__ bsum,
                  int* __restrict__ start, int* __restrict__ cur, int n, int total){
    __shared__ int a[256], b[256];
    int t = threadIdx.x;
    int i = blockIdx.x * 256 + t;
    int orig = (i < n) ? deg[i] : 0;
    int *src = a, *dst = b;
    src[t] = orig;
    __syncthreads();
    for (int off = 1; off < 256; off <<= 1){
        dst[t] = src[t] + ((t >= off) ? src[t-off] : 0);
        __syncthreads();
        int* tmp = src; src = dst; dst = tmp;
    }
    int excl = src[t] - orig + bsum[blockIdx.x];
    if (i < n){ start[i] = excl; cur[i] = excl; }
    if (i == n-1) start[n] = total;
}

__global__ __launch_bounds__(256)
void k_fill_gcn(const int* __restrict__ eidx, const float* __restrict__ ew,
                int* __restrict__ cur, int* __restrict__ colp, float* __restrict__ wp, int E){
    int i = blockIdx.x * 256 + threadIdx.x;
    if (i < E){
        int r = eidx[i];
        int pos = atomicAdd(&cur[r], 1);
        colp[pos] = eidx[E + i];
        wp[pos]   = ew[i];
    }
}

__global__ __launch_bounds__(256)
void k_fill_gat(const int* __restrict__ beidx, int* __restrict__ cur,
                int* __restrict__ colp, int E2){
    int i = blockIdx.x * 256 + threadIdx.x;
    if (i < E2){
        int r = beidx[i];
        int pos = atomicAdd(&cur[r], 1);
        colp[pos] = beidx[E2 + i];
    }
}

// ---------------- GCN pull + normalize + gat_w matvec + attention scalars ----------------
template<int R>
__global__ __launch_bounds__(128)
void k_gcn_pull_fin(const float* __restrict__ gcn_in,
                    const int* __restrict__ start, const int* __restrict__ colp,
                    const float* __restrict__ wp,
                    const float* __restrict__ lmbda,
                    const float* __restrict__ gat_w, const float* __restrict__ gat_b,
                    const float* __restrict__ watt,
                    float* __restrict__ gat_in,
                    float* __restrict__ dl, float* __restrict__ dr, int n)
{
    const int j = threadIdx.x;
    const int row0 = blockIdx.x * R;
    __shared__ float sh[R*D];
    __shared__ float red[R*D];
    float l1 = lmbda[0], l2 = lmbda[1];

    #pragma unroll
    for (int r = 0; r < R; ++r){
        int rr = row0 + r;
        if (rr < n){
            float acc = 0.0f, wsum = 0.0f;
            int s0 = start[rr], s1 = start[rr+1];
            for (int e = s0; e < s1; ++e){
                int   c = colp[e];
                float w = wp[e];
                acc  += w * gcn_in[(size_t)c * D + j];
                wsum += w;
            }
            float base = gcn_in[(size_t)rr * D + j];
            sh[r*D + j] = (base + l2 * acc) / (1.0f + l2 * wsum) * l1;
        } else {
            sh[r*D + j] = 0.0f;
        }
    }
    __syncthreads();

    float gv[R]; matvec<R>(sh, gat_w, gat_b, j, gv);
    #pragma unroll
    for (int r = 0; r < R; ++r){
        int rr = row0 + r;
        if (rr < n) gat_in[(size_t)rr * D + j] = gv[r];
    }

    float wl = watt[j], wr = watt[D + j];
    __syncthreads();
    #pragma unroll
    for (int r = 0; r < R; ++r) red[r*D + j] = gv[r] * wl;
    multiReduce<R>(red, j);
    if (j == 0){
        #pragma unroll
        for (int r = 0; r < R; ++r){ int rr = row0 + r; if (rr < n) dl[rr] = red[r*D]; }
    }
    __syncthreads();
    #pragma unroll
    for (int r = 0; r < R; ++r) red[r*D + j] = gv[r] * wr;
    multiReduce<R>(red, j);
    if (j == 0){
        #pragma unroll
        for (int r = 0; r < R; ++r){ int rr = row0 + r; if (rr < n) dr[rr] = red[r*D]; }
    }
}

// ---------------- GAT pull + normalize + PReLU -> out ----------------
template<int R>
__global__ __launch_bounds__(128)
void k_gat_out(const float* __restrict__ gat_in,
               const int* __restrict__ start2, const int* __restrict__ colp2,
               const int* __restrict__ bids,
               const float* __restrict__ dl, const float* __restrict__ dr,
               const float* __restrict__ prelu_a,
               float* __restrict__ out, int n)
{
    const int j = threadIdx.x;
    const int row0 = blockIdx.x * R;
    float pa = prelu_a[0];

    #pragma unroll
    for (int r = 0; r < R; ++r){
        int rr = row0 + r;
        if (rr < n){
            float dlv = dl[bids[rr]];
            int s0 = start2[rr], s1 = start2[rr+1];
            float acc = 0.0f, es = 0.0f;
            for (int e = s0; e < s1; ++e){
                int c = colp2[e];
                float ev = dlv + dr[c];
                float lr = ev > 0.0f ? ev : 0.2f * ev;
                float att = __expf(-lr);
                es  += att;
                acc += att * gat_in[(size_t)c * D + j];
            }
            float v = acc / es;   // every GAT row has its self-loop -> es > 0
            out[(size_t)rr * D + j] = v > 0.0f ? v : pa * v;
        }
    }
}

// ---------------- launch ----------------

extern "C" void kernel_launch(void* const* d_in, const int* in_sizes, int n_in,
                              void* d_out, int out_size, void* d_ws, size_t ws_size,
                              hipStream_t stream)
{
    const float* ent   = (const float*)d_in[0];
    const float* ew    = (const float*)d_in[1];
    const float* ln1_g = (const float*)d_in[2];
    const float* ln1_b = (const float*)d_in[3];
    // d_in[4..7] = wq,bq,wk,bk : dead (softmax over size-1 axis == 1 -> ctx == v)
    const float* wv    = (const float*)d_in[8];
    const float* bv    = (const float*)d_in[9];
    const float* wo    = (const float*)d_in[10];
    const float* bo    = (const float*)d_in[11];
    const float* ln2_g = (const float*)d_in[12];
    const float* ln2_b = (const float*)d_in[13];
    const float* w1    = (const float*)d_in[14];
    const float* b1    = (const float*)d_in[15];
    const float* w2    = (const float*)d_in[16];
    const float* b2    = (const float*)d_in[17];
    const float* lmbda = (const float*)d_in[18];
    const float* gat_w = (const float*)d_in[19];
    const float* gat_b = (const float*)d_in[20];
    const float* watt  = (const float*)d_in[21];
    const float* prelu = (const float*)d_in[22];
    const int* eidx    = (const int*)d_in[23];
    const int* bids    = (const int*)d_in[24];
    const int* beidx   = (const int*)d_in[25];

    const int n  = in_sizes[24];        // N entities
    const int E  = in_sizes[1];         // KG edges
    const int E2 = in_sizes[25] / 2;    // batch edges (E + N self loops)

    char* ws = (char*)d_ws;
    const size_t szND = (size_t)n * D * sizeof(float);
    size_t off = 0;
    float* bufA   = (float*)(ws + off); off += szND;                    // gcn_in
    float* bufB   = (float*)(ws + off); off += szND;                    // gat_in
    float* dl     = (float*)(ws + off); off += (size_t)n * 4;
    float* dr     = (float*)(ws + off); off += (size_t)n * 4;
    int*   deg1   = (int*)(ws + off);   off += (size_t)n * 4;           // deg1+deg2 adjacent
    int*   deg2   = (int*)(ws + off);   off += (size_t)n * 4;           //  -> single memset
    int*   start1 = (int*)(ws + off);   off += (size_t)(n+1) * 4;
    int*   start2 = (int*)(ws + off);   off += (size_t)(n+1) * 4;
    int*   cur1   = (int*)(ws + off);   off += (size_t)n * 4;
    int*   cur2   = (int*)(ws + off);   off += (size_t)n * 4;
    int*   bsum   = (int*)(ws + off);   off += 1024 * 4;
    int*   colp1  = (int*)(ws + off);   off += (size_t)E * 4;
    float* wp1    = (float*)(ws + off); off += (size_t)E * 4;
    int*   colp2  = (int*)(ws + off);   off += (size_t)E2 * 4;

    constexpr int R = 4;
    const int nblk  = (n + R - 1) / R;
    const int nscan = (n + 255) / 256;

    // dense block: readlane form, 16 rows per 64-thread block
    k_dense<<<(n + RB - 1)/RB, 64, 0, stream>>>(ent, ln1_g, ln1_b, wv, bv, wo, bo,
                                                ln2_g, ln2_b, w1, b1, w2, b2, bufA, n);

    // CSR build (both edge sets)
    hipMemsetAsync(deg1, 0, (size_t)2 * n * 4, stream);
    k_hist<<<(E + 255)/256, 256, 0, stream>>>(eidx, deg1, E);
    k_hist<<<(E2 + 255)/256, 256, 0, stream>>>(beidx, deg2, E2);

    k_scan_partial<<<nscan, 256, 0, stream>>>(deg1, bsum, n);
    k_scan_bsums<<<1, 1024, 0, stream>>>(bsum, nscan);
    k_scan_final<<<nscan, 256, 0, stream>>>(deg1, bsum, start1, cur1, n, E);
    k_fill_gcn<<<(E + 255)/256, 256, 0, stream>>>(eidx, ew, cur1, colp1, wp1, E);

    k_scan_partial<<<nscan, 256, 0, stream>>>(deg2, bsum, n);
    k_scan_bsums<<<1, 1024, 0, stream>>>(bsum, nscan);
    k_scan_final<<<nscan, 256, 0, stream>>>(deg2, bsum, start2, cur2, n, E2);
    k_fill_gat<<<(E2 + 255)/256, 256, 0, stream>>>(beidx, cur2, colp2, E2);

    // GCN pull (+ gat_w matvec + attention scalars), no atomics
    k_gcn_pull_fin<R><<<nblk, 128, 0, stream>>>(bufA, start1, colp1, wp1, lmbda,
                                                gat_w, gat_b, watt, bufB, dl, dr, n);

    // GAT pull + PReLU -> out, no atomics
    k_gat_out<R><<<nblk, 128, 0, stream>>>(bufB, start2, colp2, bids, dl, dr,
                                           prelu, (float*)d_out, n);
}